// Round 22
// baseline (452.936 us; speedup 1.0000x reference)
//
#include <hip/hip_runtime.h>
#include <hip/hip_bf16.h>

#define NB 128
#define NT 256
#define NC 768
#define NL 576

// ---- workspace layout (float offsets), all < 1.3 MB; ssms at 2 MiB+ ----
constexpr size_t OFF_P1    = 4096;     // 65536: per-ssm-row {1-corr, sqdiff}
constexpr size_t OFF_WON   = 135168;   // 32768: waves online
constexpr size_t OFF_WTG   = 167936;   // 32768: waves target
constexpr size_t OFF_PW    = 200704;   // 256:   per-batch wave {1-corr, sqdiff}
constexpr size_t OFF_FRQ   = 200960;   // 8192:  per (b,k) wave PSD bin
constexpr size_t OFF_RG    = 209280;   // 32640: per (b,diag) std*m/20
constexpr size_t OFF_RPG   = 241920;   // 384:   per-batch {temporal, psd-pearson, partition}
constexpr size_t OFF_SO    = 242304;   // 36864: rppg online PSD (b*288+k)
constexpr size_t OFF_ST    = 279168;   // 36864: rppg target PSD
constexpr size_t OFF_SSM_ON_B = (size_t)2 * 1024 * 1024;                 // bytes
constexpr size_t OFF_SSM_TG_B = OFF_SSM_ON_B + (size_t)NB * NT * NT * 2; // bytes

typedef __attribute__((ext_vector_type(8))) short short8v;   // 8 bf16 (4 VGPR)
typedef __attribute__((ext_vector_type(4))) float f32x4;     // MFMA acc

__device__ __forceinline__ unsigned short f2bf(float f) {
    __hip_bfloat16 h = __float2bfloat16(f);
    unsigned short u; __builtin_memcpy(&u, &h, 2); return u;
}
__device__ __forceinline__ float bf2f(unsigned short u) {
    __hip_bfloat16 h; __builtin_memcpy(&h, &u, 2); return __bfloat162float(h);
}

// libm-free sin/cos of 2*pi*x, |err| < 3e-5
__device__ __forceinline__ float sin2pi(float x) {
    x -= floorf(x + 0.5f);
    float x2 = x * x;
    float p = 3.8199526f;
    p = p * x2 - 15.094643f;
    p = p * x2 + 42.058693f;
    p = p * x2 - 76.705860f;
    p = p * x2 + 81.605249f;
    p = p * x2 - 41.341702f;
    p = p * x2 + 6.2831853f;
    return p * x;
}
__device__ __forceinline__ float cos2pi(float x) { return sin2pi(x + 0.25f); }

__device__ __forceinline__ float blockSum(float v, float* tmp) {
    int lane = threadIdx.x & 63, wid = threadIdx.x >> 6;
#pragma unroll
    for (int o = 32; o; o >>= 1) v += __shfl_down(v, o, 64);
    __syncthreads();
    if (lane == 0) tmp[wid] = v;
    __syncthreads();
    return tmp[0] + tmp[1] + tmp[2] + tmp[3];
}
__device__ __forceinline__ float blockMax(float v, float* tmp) {
    int lane = threadIdx.x & 63, wid = threadIdx.x >> 6;
#pragma unroll
    for (int o = 32; o; o >>= 1) v = fmaxf(v, __shfl_down(v, o, 64));
    __syncthreads();
    if (lane == 0) tmp[wid] = v;
    __syncthreads();
    return fmaxf(fmaxf(tmp[0], tmp[1]), fmaxf(tmp[2], tmp[3]));
}
__device__ __forceinline__ float pearson1m(float S0, float S1, float S2, float S3,
                                           float S4, float n) {
    float cov = (S4 - S0 * S1 / n) / (n - 1.f);
    float xs = sqrtf(fmaxf((S2 - S0 * S0 / n) / (n - 1.f), 0.f));
    float ys = sqrtf(fmaxf((S3 - S1 * S1 / n) / (n - 1.f), 0.f));
    float corr = fminf(1.f, fmaxf(-1.f, cov / (xs * ys + 1e-7f)));
    return 1.f - corr;
}

// ======== MFMA cosine-sim gram: ROWSTR 36 so LDS fits 8 blocks/CU ========
#define ROWSTR 36
#define LDS_HALF8 (128 * ROWSTR)
__global__ __launch_bounds__(256) void gram8_k(const float* __restrict__ on,
                                               const float* __restrict__ tg,
                                               unsigned short* __restrict__ ssm_on,
                                               unsigned short* __restrict__ ssm_tg) {
    __shared__ unsigned short lds[2 * LDS_HALF8];
    __shared__ float invs[128];
    int lin = blockIdx.x;
    int xcd = lin & 7, m = lin >> 3;
    int pair = (m >> 4) * 8 + xcd;
    int tile = m & 15;
    int rt = tile >> 2, ct = tile & 3;
    int b = pair >> 1, tau = pair & 1;
    const float* X = tau ? tg : on;
    unsigned short* S = (tau ? ssm_tg : ssm_on) + (size_t)b * NT * NT;

    int t = threadIdx.x;
    int wave = t >> 6, lane = t & 63;
    int fr = lane & 15, fq = lane >> 4;
    int wr = (wave >> 1) * 32, wc = (wave & 1) * 32;

    int rl = t >> 1, h = t & 1;
    int grow = (rl < 64) ? (rt * 64 + rl) : (ct * 64 + (rl - 64));
    const float* src = X + ((size_t)b * NT + grow) * NC + h * 16;
    int stoff = rl * ROWSTR + h * 16;
    float sq = 0.f;

    int offA0 = (wr + fr) * ROWSTR + 8 * fq;
    int offA1 = (wr + 16 + fr) * ROWSTR + 8 * fq;
    int offB0 = (64 + wc + fr) * ROWSTR + 8 * fq;
    int offB1 = (64 + wc + 16 + fr) * ROWSTR + 8 * fq;

    f32x4 acc[2][2] = {};

    {
        float4 a = *reinterpret_cast<const float4*>(src);
        float4 bb = *reinterpret_cast<const float4*>(src + 4);
        float4 cc = *reinterpret_cast<const float4*>(src + 8);
        float4 d = *reinterpret_cast<const float4*>(src + 12);
        sq += a.x * a.x + a.y * a.y + a.z * a.z + a.w * a.w;
        sq += bb.x * bb.x + bb.y * bb.y + bb.z * bb.z + bb.w * bb.w;
        sq += cc.x * cc.x + cc.y * cc.y + cc.z * cc.z + cc.w * cc.w;
        sq += d.x * d.x + d.y * d.y + d.z * d.z + d.w * d.w;
        short8v v0, v1;
        v0[0] = (short)f2bf(a.x); v0[1] = (short)f2bf(a.y);
        v0[2] = (short)f2bf(a.z); v0[3] = (short)f2bf(a.w);
        v0[4] = (short)f2bf(bb.x); v0[5] = (short)f2bf(bb.y);
        v0[6] = (short)f2bf(bb.z); v0[7] = (short)f2bf(bb.w);
        v1[0] = (short)f2bf(cc.x); v1[1] = (short)f2bf(cc.y);
        v1[2] = (short)f2bf(cc.z); v1[3] = (short)f2bf(cc.w);
        v1[4] = (short)f2bf(d.x); v1[5] = (short)f2bf(d.y);
        v1[6] = (short)f2bf(d.z); v1[7] = (short)f2bf(d.w);
        *reinterpret_cast<short8v*>(&lds[stoff]) = v0;
        *reinterpret_cast<short8v*>(&lds[stoff + 8]) = v1;
    }
    __syncthreads();

    int cur = 0;
#pragma unroll 1
    for (int s = 0; s < 24; s++) {
        unsigned short* rb = &lds[cur * LDS_HALF8];
        short8v A0 = *reinterpret_cast<short8v*>(rb + offA0);
        short8v A1 = *reinterpret_cast<short8v*>(rb + offA1);
        short8v B0 = *reinterpret_cast<short8v*>(rb + offB0);
        short8v B1 = *reinterpret_cast<short8v*>(rb + offB1);
        float4 a, bb, cc, d;
        if (s < 23) {
            const float* p = src + 32 * (s + 1);
            a = *reinterpret_cast<const float4*>(p);
            bb = *reinterpret_cast<const float4*>(p + 4);
            cc = *reinterpret_cast<const float4*>(p + 8);
            d = *reinterpret_cast<const float4*>(p + 12);
        }
        acc[0][0] = __builtin_amdgcn_mfma_f32_16x16x32_bf16(A0, B0, acc[0][0], 0, 0, 0);
        acc[0][1] = __builtin_amdgcn_mfma_f32_16x16x32_bf16(A0, B1, acc[0][1], 0, 0, 0);
        acc[1][0] = __builtin_amdgcn_mfma_f32_16x16x32_bf16(A1, B0, acc[1][0], 0, 0, 0);
        acc[1][1] = __builtin_amdgcn_mfma_f32_16x16x32_bf16(A1, B1, acc[1][1], 0, 0, 0);
        if (s < 23) {
            unsigned short* wbuf = &lds[(cur ^ 1) * LDS_HALF8];
            sq += a.x * a.x + a.y * a.y + a.z * a.z + a.w * a.w;
            sq += bb.x * bb.x + bb.y * bb.y + bb.z * bb.z + bb.w * bb.w;
            sq += cc.x * cc.x + cc.y * cc.y + cc.z * cc.z + cc.w * cc.w;
            sq += d.x * d.x + d.y * d.y + d.z * d.z + d.w * d.w;
            short8v v0, v1;
            v0[0] = (short)f2bf(a.x); v0[1] = (short)f2bf(a.y);
            v0[2] = (short)f2bf(a.z); v0[3] = (short)f2bf(a.w);
            v0[4] = (short)f2bf(bb.x); v0[5] = (short)f2bf(bb.y);
            v0[6] = (short)f2bf(bb.z); v0[7] = (short)f2bf(bb.w);
            v1[0] = (short)f2bf(cc.x); v1[1] = (short)f2bf(cc.y);
            v1[2] = (short)f2bf(cc.z); v1[3] = (short)f2bf(cc.w);
            v1[4] = (short)f2bf(d.x); v1[5] = (short)f2bf(d.y);
            v1[6] = (short)f2bf(d.z); v1[7] = (short)f2bf(d.w);
            *reinterpret_cast<short8v*>(wbuf + stoff) = v0;
            *reinterpret_cast<short8v*>(wbuf + stoff + 8) = v1;
        }
        __syncthreads();
        cur ^= 1;
    }
    {
        float v = sq + __shfl_xor(sq, 1, 64);
        if (h == 0) invs[rl] = 1.f / sqrtf(v);
    }
    __syncthreads();
#pragma unroll
    for (int f = 0; f < 2; f++) {
        int rowl = wr + 16 * f + 4 * fq;
#pragma unroll
        for (int g = 0; g < 2; g++) {
            int coll = wc + 16 * g + fr;
            float ic = invs[64 + coll];
            int gcol = ct * 64 + coll;
#pragma unroll
            for (int r = 0; r < 4; r++)
                S[(size_t)(rt * 64 + rowl + r) * NT + gcol] =
                    f2bf(acc[f][g][r] * invs[rowl + r] * ic);
        }
    }
}

// ======== mega1: rppg-DFT (36864) | ssm-row pearson (32768) | reg diag (32640) ========
__global__ __launch_bounds__(256) void mega1_k(const float* __restrict__ rppg_on,
                                               const float* __restrict__ rppg_tg,
                                               const unsigned short* __restrict__ ssm_on,
                                               const unsigned short* __restrict__ ssm_tg,
                                               float* __restrict__ ws) {
    __shared__ float tmp6[4][6];
    float* tmp = &tmp6[0][0];     // 4-float scratch (strided use is fine: wid<4 -> tmp6[wid][0])
    int bid = blockIdx.x, t = threadIdx.x;
    int lane = t & 63, wid = t >> 6;

    if (bid < 36864) {
        // ---- rppg DFT bin + fused temporal pearson at k==0 ----
        int k = bid % 288, b = bid / 288;
        const float* po = rppg_on + (size_t)b * NL;
        const float* pg = rppg_tg + (size_t)b * NL;
        float o1 = po[t], g1 = pg[t];
        float o2 = po[t + 256], g2 = pg[t + 256];
        bool h3 = t < 64;
        float o3 = h3 ? po[t + 512] : 0.f, g3 = h3 ? pg[t + 512] : 0.f;
        if (k == 0) {
            float S0 = blockSum(o1 + o2 + o3, tmp);
            float S1 = blockSum(g1 + g2 + g3, tmp);
            float S2 = blockSum(o1 * o1 + o2 * o2 + o3 * o3, tmp);
            float S3 = blockSum(g1 * g1 + g2 * g2 + g3 * g3, tmp);
            float S4 = blockSum(o1 * g1 + o2 * g2 + o3 * g3, tmp);
            if (t == 0) ws[OFF_RPG + 3 * b + 0] = pearson1m(S0, S1, S2, S3, S4, 576.f);
            __syncthreads();
        }
        float reo, imo, reg_, img;
        {
            float x1 = (float)((t * k) % NL) * (1.f / 576.f);
            float c1 = cos2pi(x1), s1 = sin2pi(x1);
            float x2 = (float)(((t + 256) * k) % NL) * (1.f / 576.f);
            float c2 = cos2pi(x2), s2 = sin2pi(x2);
            reo = o1 * c1 + o2 * c2; imo = o1 * s1 + o2 * s2;
            reg_ = g1 * c1 + g2 * c2; img = g1 * s1 + g2 * s2;
            if (h3) {
                float x3 = (float)(((t + 512) * k) % NL) * (1.f / 576.f);
                float c3 = cos2pi(x3), s3 = sin2pi(x3);
                reo = fmaf(o3, c3, reo); imo = fmaf(o3, s3, imo);
                reg_ = fmaf(g3, c3, reg_); img = fmaf(g3, s3, img);
            }
        }
        float RO = blockSum(reo, tmp);
        float IO = blockSum(imo, tmp);
        float RG = blockSum(reg_, tmp);
        float IG = blockSum(img, tmp);
        if (t == 0) {
            ws[OFF_SO + b * 288 + k] = RO * RO + IO * IO;
            ws[OFF_ST + b * 288 + k] = RG * RG + IG * IG;
        }
    } else if (bid < 69632) {
        // ---- per-ssm-row pearson + sqdiff + wave emit (single-barrier 6-reduce) ----
        int row = bid - 36864;
        size_t base = (size_t)row * NT;
        float o = bf2f(ssm_on[base + t]), g = bf2f(ssm_tg[base + t]);
        float v6[6] = {o, g, o * o, g * g, o * g, (o - g) * (o - g)};
#pragma unroll
        for (int j = 0; j < 6; j++) {
            float x = v6[j];
#pragma unroll
            for (int off = 32; off; off >>= 1) x += __shfl_down(x, off, 64);
            v6[j] = x;
        }
        if (lane == 0) {
#pragma unroll
            for (int j = 0; j < 6; j++) tmp6[wid][j] = v6[j];
        }
        __syncthreads();
        if (t == 0) {
            float S[6];
#pragma unroll
            for (int j = 0; j < 6; j++)
                S[j] = tmp6[0][j] + tmp6[1][j] + tmp6[2][j] + tmp6[3][j];
            ws[OFF_P1 + 2 * row + 0] = pearson1m(S[0], S[1], S[2], S[3], S[4], 256.f);
            ws[OFF_P1 + 2 * row + 1] = S[5];
            ws[OFF_WON + row] = S[0] * (1.f / NT);
            ws[OFF_WTG + row] = S[1] * (1.f / NT);
        }
    } else {
        // ---- reg diagonal: one block per (b, d) ----
        int q = bid - 69632;
        int b = q / 255, d = q % 255 + 1;
        int col = t + d;
        bool ok = col < 256;
        float v = 0.f;
        if (ok) v = bf2f(ssm_on[(size_t)b * NT * NT + t * NT + col]);
        float s1 = blockSum(v, tmp);
        float s2 = blockSum(v * v, tmp);
        if (t == 0) {
            float outv = 0.f;
            if (d <= 254) {
                float mm = (float)(256 - d);
                float var = (s2 - s1 * s1 / mm) / (mm - 1.f);
                outv = sqrtf(fmaxf(var, 0.f)) * mm * 0.05f;
            }
            ws[OFF_RG + b * 255 + (d - 1)] = outv;
        }
    }
}

// ======== mega2: freq bins (8192) | wave pearson (128) | rppg finalize (128) ========
__global__ __launch_bounds__(256) void mega2_k(float* __restrict__ ws) {
    __shared__ float tmp[4];
    int bid = blockIdx.x, t = threadIdx.x;

    if (bid < 8192) {
        int k = bid & 63, b = bid >> 6;
        float val = ws[OFF_WON + b * NT + t];
        float x = (float)((t * k) & 255) * (1.f / 256.f);
        float re = blockSum(val * cos2pi(x), tmp);
        float im = blockSum(val * sin2pi(x), tmp);
        if (t == 0) ws[OFF_FRQ + b * 64 + k] = re * re + im * im;
    } else if (bid < 8320) {
        int b = bid - 8192;
        float o = ws[OFF_WON + b * NT + t], g = ws[OFF_WTG + b * NT + t];
        float S0 = blockSum(o, tmp);
        float S1 = blockSum(g, tmp);
        float S2 = blockSum(o * o, tmp);
        float S3 = blockSum(g * g, tmp);
        float S4 = blockSum(o * g, tmp);
        float S5 = blockSum((o - g) * (o - g), tmp);
        if (t == 0) {
            ws[OFF_PW + 2 * b + 0] = pearson1m(S0, S1, S2, S3, S4, 256.f);
            ws[OFF_PW + 2 * b + 1] = S5;
        }
    } else {
        int b = bid - 8320;
        const float* SO = ws + OFF_SO + (size_t)b * 288;
        const float* ST = ws + OFF_ST + (size_t)b * 288;
        float a0 = SO[t], b0 = ST[t];
        bool h2 = t < 32;
        float a1 = h2 ? SO[t + 256] : 0.f, b1 = h2 ? ST[t + 256] : 0.f;
        float Mo = blockMax(fmaxf(a0, a1), tmp);
        float Mg = blockMax(fmaxf(b0, b1), tmp);
        if (Mo <= 0.f) Mo = 1.f;
        if (Mg <= 0.f) Mg = 1.f;
        float n0 = a0 / Mo, m0 = b0 / Mg;
        float n1 = a1 / Mo, m1 = b1 / Mg;
        float S0 = blockSum(n0 + n1, tmp);
        float S1 = blockSum(m0 + m1, tmp);
        float S2 = blockSum(n0 * n0 + n1 * n1, tmp);
        float S3 = blockSum(m0 * m0 + m1 * m1, tmp);
        float S4 = blockSum(n0 * m0 + n1 * m1, tmp);
        float bt0 = (t >= 9 && t < 57) ? a0 : 0.f;
        float TT = blockSum(a0 + a1, tmp);
        float TB = blockSum(bt0, tmp);
        if (t == 0) {
            ws[OFF_RPG + 3 * b + 1] = pearson1m(S0, S1, S2, S3, S4, 288.f);
            ws[OFF_RPG + 3 * b + 2] = (TB > 0.f) ? (TT / TB - 1.f) : 0.f;
        }
    }
}

// ======== final combine (absorbs freq finalize) — FLOAT32 outputs ========
__global__ __launch_bounds__(256) void final_k(const float* __restrict__ ws,
                                               float* __restrict__ out) {
    __shared__ float tmp[4];
    int tid = threadIdx.x;
    const float* p1 = ws + OFF_P1;
    float a = 0.f, bsum = 0.f;
    for (int i = tid; i < 32768; i += 256) { a += p1[2 * i]; bsum += p1[2 * i + 1]; }
    float S0 = blockSum(a, tmp);
    float S1 = blockSum(bsum, tmp);
    const float* pw = ws + OFF_PW;
    float c0 = 0.f, c1 = 0.f;
    for (int i = tid; i < 128; i += 256) { c0 += pw[2 * i]; c1 += pw[2 * i + 1]; }
    float W0 = blockSum(c0, tmp);
    float W1 = blockSum(c1, tmp);
    const float* frq = ws + OFF_FRQ;
    float fqv = 0.f;
    if (tid < 128) {
        float Ft = 0.f, Fb = 0.f;
        for (int k = 0; k < 64; k++) {
            float v = frq[tid * 64 + k];
            Ft += v;
            if (k >= 2 && k < 12) Fb += v;
        }
        if (Fb > 0.f) fqv = Ft / Fb - 1.f;
    }
    float Fq = blockSum(fqv, tmp);
    const float* rg = ws + OFF_RG;
    float e = 0.f;
    for (int i = tid; i < 32640; i += 256) e += rg[i];
    float Rg = blockSum(e, tmp);
    const float* tq = ws + OFF_RPG;
    float g0 = 0.f, g1 = 0.f, g2 = 0.f;
    for (int i = tid; i < 128; i += 256) {
        g0 += tq[3 * i]; g1 += tq[3 * i + 1]; g2 += tq[3 * i + 2];
    }
    float R0 = blockSum(g0, tmp);
    float R1 = blockSum(g1, tmp);
    float R2 = blockSum(g2, tmp);
    if (tid == 0) {
        float loss_pyr  = 0.5f * (S1 / 8388608.f + W1 / 32768.f + S0 / 32768.f + W0 / 128.f);
        float loss_r    = 0.5f * Rg / (128.f * 254.f);
        float loss_f    = 0.2f * Fq / 128.f;
        float loss_rppg = 0.5f * (R0 + R1 + R2) / 128.f;
        float total = loss_rppg + loss_pyr + loss_r + loss_f;
        out[0] = total;
        out[1] = loss_pyr;
        out[2] = loss_rppg;
        out[3] = loss_r;
        out[4] = loss_f;
    }
}

extern "C" void kernel_launch(void* const* d_in, const int* in_sizes, int n_in,
                              void* d_out, int out_size, void* d_ws, size_t ws_size,
                              hipStream_t stream) {
    const float* pyr_on  = (const float*)d_in[0];
    const float* pyr_tg  = (const float*)d_in[1];
    const float* rppg_on = (const float*)d_in[2];
    const float* rppg_tg = (const float*)d_in[3];
    float* ws = (float*)d_ws;
    unsigned short* ssm_on = (unsigned short*)((char*)d_ws + OFF_SSM_ON_B);
    unsigned short* ssm_tg = (unsigned short*)((char*)d_ws + OFF_SSM_TG_B);
    float* out = (float*)d_out;

    gram8_k<<<4096, 256, 0, stream>>>(pyr_on, pyr_tg, ssm_on, ssm_tg);
    mega1_k<<<102272, 256, 0, stream>>>(rppg_on, rppg_tg, ssm_on, ssm_tg, ws);
    mega2_k<<<8448, 256, 0, stream>>>(ws);
    final_k<<<1, 256, 0, stream>>>(ws, out);
}

// Round 23
// 311.167 us; speedup vs baseline: 1.4556x; 1.4556x over previous
//
#include <hip/hip_runtime.h>
#include <hip/hip_bf16.h>

#define NB 128
#define NT 256
#define NC 768
#define NL 576

// ---- workspace layout (float offsets), all < 1.3 MB; ssms at 2 MiB+ ----
constexpr size_t OFF_P1    = 4096;     // 65536: per-ssm-row {1-corr, sqdiff}
constexpr size_t OFF_WON   = 135168;   // 32768: waves online
constexpr size_t OFF_WTG   = 167936;   // 32768: waves target
constexpr size_t OFF_PW    = 200704;   // 256:   per-batch wave {1-corr, sqdiff}
constexpr size_t OFF_FRQ   = 200960;   // 8192:  per (b,k) wave PSD bin
constexpr size_t OFF_RG    = 209280;   // 32640: per (b,diag) std*m/20
constexpr size_t OFF_RPG   = 241920;   // 384:   per-batch {temporal, psd-pearson, partition}
constexpr size_t OFF_SO    = 242304;   // 36864: rppg online PSD (b*288+k)
constexpr size_t OFF_ST    = 279168;   // 36864: rppg target PSD
constexpr size_t OFF_SSM_ON_B = (size_t)2 * 1024 * 1024;                 // bytes
constexpr size_t OFF_SSM_TG_B = OFF_SSM_ON_B + (size_t)NB * NT * NT * 2; // bytes

typedef __attribute__((ext_vector_type(8))) short short8v;   // 8 bf16 (4 VGPR)
typedef __attribute__((ext_vector_type(4))) float f32x4;     // MFMA acc

__device__ __forceinline__ unsigned short f2bf(float f) {
    __hip_bfloat16 h = __float2bfloat16(f);
    unsigned short u; __builtin_memcpy(&u, &h, 2); return u;
}
__device__ __forceinline__ float bf2f(unsigned short u) {
    __hip_bfloat16 h; __builtin_memcpy(&h, &u, 2); return __bfloat162float(h);
}

// libm-free sin/cos of 2*pi*x, |err| < 3e-5
__device__ __forceinline__ float sin2pi(float x) {
    x -= floorf(x + 0.5f);
    float x2 = x * x;
    float p = 3.8199526f;
    p = p * x2 - 15.094643f;
    p = p * x2 + 42.058693f;
    p = p * x2 - 76.705860f;
    p = p * x2 + 81.605249f;
    p = p * x2 - 41.341702f;
    p = p * x2 + 6.2831853f;
    return p * x;
}
__device__ __forceinline__ float cos2pi(float x) { return sin2pi(x + 0.25f); }

__device__ __forceinline__ float blockSum(float v, float* tmp) {
    int lane = threadIdx.x & 63, wid = threadIdx.x >> 6;
#pragma unroll
    for (int o = 32; o; o >>= 1) v += __shfl_down(v, o, 64);
    __syncthreads();
    if (lane == 0) tmp[wid] = v;
    __syncthreads();
    return tmp[0] + tmp[1] + tmp[2] + tmp[3];
}
__device__ __forceinline__ float blockMax(float v, float* tmp) {
    int lane = threadIdx.x & 63, wid = threadIdx.x >> 6;
#pragma unroll
    for (int o = 32; o; o >>= 1) v = fmaxf(v, __shfl_down(v, o, 64));
    __syncthreads();
    if (lane == 0) tmp[wid] = v;
    __syncthreads();
    return fmaxf(fmaxf(tmp[0], tmp[1]), fmaxf(tmp[2], tmp[3]));
}
__device__ __forceinline__ float pearson1m(float S0, float S1, float S2, float S3,
                                           float S4, float n) {
    float cov = (S4 - S0 * S1 / n) / (n - 1.f);
    float xs = sqrtf(fmaxf((S2 - S0 * S0 / n) / (n - 1.f), 0.f));
    float ys = sqrtf(fmaxf((S3 - S1 * S1 / n) / (n - 1.f), 0.f));
    float corr = fminf(1.f, fmaxf(-1.f, cov / (xs * ys + 1e-7f)));
    return 1.f - corr;
}

// ======== MFMA cosine-sim gram: [128][32] chunk-XOR swizzle, invs in LDS overlay ========
// grid 4096: xcd=lin&7, m=lin>>3; pair=(m>>4)*8+xcd; tile=m&15 (rt=tile>>2, ct=tile&3).
// Block 256 thr / 4 waves; wave owns 32x32 quadrant. LDS 2 x [128][32] bf16 = 16 KB
// (16B-aligned 64B row stride; 8-elem chunk c stored at c ^ ((row>>1)&3) -> 0 conflicts,
// verified r17). Staging 2 thr/row x 16 floats; fused sumsq -> invs written into dead LDS.
#define LDS_HALF9 (128 * 32)
__global__ __launch_bounds__(256) void gram9_k(const float* __restrict__ on,
                                               const float* __restrict__ tg,
                                               unsigned short* __restrict__ ssm_on,
                                               unsigned short* __restrict__ ssm_tg) {
    __shared__ unsigned short lds[2 * LDS_HALF9];
    int lin = blockIdx.x;
    int xcd = lin & 7, m = lin >> 3;
    int pair = (m >> 4) * 8 + xcd;
    int tile = m & 15;
    int rt = tile >> 2, ct = tile & 3;
    int b = pair >> 1, tau = pair & 1;
    const float* X = tau ? tg : on;
    unsigned short* S = (tau ? ssm_tg : ssm_on) + (size_t)b * NT * NT;

    int t = threadIdx.x;
    int wave = t >> 6, lane = t & 63;
    int fr = lane & 15, fq = lane >> 4;
    int wr = (wave >> 1) * 32, wc = (wave & 1) * 32;

    // staging: row rl = t>>1, half h = t&1 covers chunks {2h, 2h+1} (16 floats)
    int rl = t >> 1, h = t & 1;
    int grow = (rl < 64) ? (rt * 64 + rl) : (ct * 64 + (rl - 64));
    const float* src = X + ((size_t)b * NT + grow) * NC + h * 16;
    int swl = (rl >> 1) & 3;
    int stoff0 = rl * 32 + 8 * ((2 * h) ^ swl);
    int stoff1 = rl * 32 + 8 * ((2 * h + 1) ^ swl);
    float sq = 0.f;

    // fragment offsets: chunk fq at fq ^ ((row>>1)&3); bases mult of 16 -> (fr>>1)&3
    int fsw = (fr >> 1) & 3;
    int offA0 = (wr + fr) * 32 + 8 * (fq ^ fsw);
    int offA1 = (wr + 16 + fr) * 32 + 8 * (fq ^ fsw);
    int offB0 = (64 + wc + fr) * 32 + 8 * (fq ^ fsw);
    int offB1 = (64 + wc + 16 + fr) * 32 + 8 * (fq ^ fsw);

    f32x4 acc[2][2] = {};

    // stage step 0
    {
        float4 a = *reinterpret_cast<const float4*>(src);
        float4 bb = *reinterpret_cast<const float4*>(src + 4);
        float4 cc = *reinterpret_cast<const float4*>(src + 8);
        float4 d = *reinterpret_cast<const float4*>(src + 12);
        sq += a.x * a.x + a.y * a.y + a.z * a.z + a.w * a.w;
        sq += bb.x * bb.x + bb.y * bb.y + bb.z * bb.z + bb.w * bb.w;
        sq += cc.x * cc.x + cc.y * cc.y + cc.z * cc.z + cc.w * cc.w;
        sq += d.x * d.x + d.y * d.y + d.z * d.z + d.w * d.w;
        short8v v0, v1;
        v0[0] = (short)f2bf(a.x); v0[1] = (short)f2bf(a.y);
        v0[2] = (short)f2bf(a.z); v0[3] = (short)f2bf(a.w);
        v0[4] = (short)f2bf(bb.x); v0[5] = (short)f2bf(bb.y);
        v0[6] = (short)f2bf(bb.z); v0[7] = (short)f2bf(bb.w);
        v1[0] = (short)f2bf(cc.x); v1[1] = (short)f2bf(cc.y);
        v1[2] = (short)f2bf(cc.z); v1[3] = (short)f2bf(cc.w);
        v1[4] = (short)f2bf(d.x); v1[5] = (short)f2bf(d.y);
        v1[6] = (short)f2bf(d.z); v1[7] = (short)f2bf(d.w);
        *reinterpret_cast<short8v*>(&lds[stoff0]) = v0;
        *reinterpret_cast<short8v*>(&lds[stoff1]) = v1;
    }
    __syncthreads();

    int cur = 0;
#pragma unroll 1
    for (int s = 0; s < 24; s++) {
        unsigned short* rb = &lds[cur * LDS_HALF9];
        short8v A0 = *reinterpret_cast<short8v*>(rb + offA0);
        short8v A1 = *reinterpret_cast<short8v*>(rb + offA1);
        short8v B0 = *reinterpret_cast<short8v*>(rb + offB0);
        short8v B1 = *reinterpret_cast<short8v*>(rb + offB1);
        float4 a, bb, cc, d;
        if (s < 23) {
            const float* p = src + 32 * (s + 1);
            a = *reinterpret_cast<const float4*>(p);
            bb = *reinterpret_cast<const float4*>(p + 4);
            cc = *reinterpret_cast<const float4*>(p + 8);
            d = *reinterpret_cast<const float4*>(p + 12);
        }
        acc[0][0] = __builtin_amdgcn_mfma_f32_16x16x32_bf16(A0, B0, acc[0][0], 0, 0, 0);
        acc[0][1] = __builtin_amdgcn_mfma_f32_16x16x32_bf16(A0, B1, acc[0][1], 0, 0, 0);
        acc[1][0] = __builtin_amdgcn_mfma_f32_16x16x32_bf16(A1, B0, acc[1][0], 0, 0, 0);
        acc[1][1] = __builtin_amdgcn_mfma_f32_16x16x32_bf16(A1, B1, acc[1][1], 0, 0, 0);
        if (s < 23) {
            unsigned short* wbuf = &lds[(cur ^ 1) * LDS_HALF9];
            sq += a.x * a.x + a.y * a.y + a.z * a.z + a.w * a.w;
            sq += bb.x * bb.x + bb.y * bb.y + bb.z * bb.z + bb.w * bb.w;
            sq += cc.x * cc.x + cc.y * cc.y + cc.z * cc.z + cc.w * cc.w;
            sq += d.x * d.x + d.y * d.y + d.z * d.z + d.w * d.w;
            short8v v0, v1;
            v0[0] = (short)f2bf(a.x); v0[1] = (short)f2bf(a.y);
            v0[2] = (short)f2bf(a.z); v0[3] = (short)f2bf(a.w);
            v0[4] = (short)f2bf(bb.x); v0[5] = (short)f2bf(bb.y);
            v0[6] = (short)f2bf(bb.z); v0[7] = (short)f2bf(bb.w);
            v1[0] = (short)f2bf(cc.x); v1[1] = (short)f2bf(cc.y);
            v1[2] = (short)f2bf(cc.z); v1[3] = (short)f2bf(cc.w);
            v1[4] = (short)f2bf(d.x); v1[5] = (short)f2bf(d.y);
            v1[6] = (short)f2bf(d.z); v1[7] = (short)f2bf(d.w);
            *reinterpret_cast<short8v*>(wbuf + stoff0) = v0;
            *reinterpret_cast<short8v*>(wbuf + stoff1) = v1;
        }
        __syncthreads();
        cur ^= 1;
    }
    // inverse norms into dead LDS (both buffers finished)
    float* invp = reinterpret_cast<float*>(lds);
    {
        float v = sq + __shfl_xor(sq, 1, 64);
        if (h == 0) invp[rl] = 1.f / sqrtf(v);
    }
    __syncthreads();
    // epilogue: C/D row = A rows (wr+16f+4*fq+r), col = B rows (wc+16g+fr)
#pragma unroll
    for (int f = 0; f < 2; f++) {
        int rowl = wr + 16 * f + 4 * fq;
#pragma unroll
        for (int g = 0; g < 2; g++) {
            int coll = wc + 16 * g + fr;
            float ic = invp[64 + coll];
            int gcol = ct * 64 + coll;
#pragma unroll
            for (int r = 0; r < 4; r++)
                S[(size_t)(rt * 64 + rowl + r) * NT + gcol] =
                    f2bf(acc[f][g][r] * invp[rowl + r] * ic);
        }
    }
}

// ======== per-ssm-row pearson + sqdiff + wave emit; single-barrier reduce ========
__global__ __launch_bounds__(256) void pearson256w_k(const unsigned short* __restrict__ A,
                                                     const unsigned short* __restrict__ Bv,
                                                     float* __restrict__ part,
                                                     float* __restrict__ won,
                                                     float* __restrict__ wtg) {
    size_t base = (size_t)blockIdx.x * NT;
    int tid = threadIdx.x;
    int lane = tid & 63, wid = tid >> 6;
    float o = bf2f(A[base + tid]), g = bf2f(Bv[base + tid]);
    float v6[6] = {o, g, o * o, g * g, o * g, (o - g) * (o - g)};
    __shared__ float tmp[4][6];
#pragma unroll
    for (int j = 0; j < 6; j++) {
        float x = v6[j];
#pragma unroll
        for (int off = 32; off; off >>= 1) x += __shfl_down(x, off, 64);
        v6[j] = x;
    }
    if (lane == 0) {
#pragma unroll
        for (int j = 0; j < 6; j++) tmp[wid][j] = v6[j];
    }
    __syncthreads();
    if (tid == 0) {
        float S[6];
#pragma unroll
        for (int j = 0; j < 6; j++)
            S[j] = tmp[0][j] + tmp[1][j] + tmp[2][j] + tmp[3][j];
        part[2 * blockIdx.x + 0] = pearson1m(S[0], S[1], S[2], S[3], S[4], 256.f);
        part[2 * blockIdx.x + 1] = S[5];
        won[blockIdx.x] = S[0] * (1.f / NT);
        wtg[blockIdx.x] = S[1] * (1.f / NT);
    }
}

// ======== wave pearson + sqdiff (f32) ========
__global__ __launch_bounds__(256) void pearsonW_k(const float* __restrict__ A,
                                                  const float* __restrict__ Bv,
                                                  float* __restrict__ part) {
    size_t base = (size_t)blockIdx.x * NT;
    int tid = threadIdx.x;
    float o = A[base + tid], g = Bv[base + tid];
    __shared__ float tmp[4];
    float S0 = blockSum(o, tmp);
    float S1 = blockSum(g, tmp);
    float S2 = blockSum(o * o, tmp);
    float S3 = blockSum(g * g, tmp);
    float S4 = blockSum(o * g, tmp);
    float S5 = blockSum((o - g) * (o - g), tmp);
    if (tid == 0) {
        part[2 * blockIdx.x + 0] = pearson1m(S0, S1, S2, S3, S4, 256.f);
        part[2 * blockIdx.x + 1] = S5;
    }
}

// ======== freq: one block per (bin k, batch b) ========
__global__ __launch_bounds__(256) void freqbin_k(const float* __restrict__ w,
                                                 float* __restrict__ frq) {
    int k = blockIdx.x, b = blockIdx.y, m = threadIdx.x;
    float val = w[b * NT + m];
    float x = (float)((m * k) & 255) * (1.f / 256.f);
    __shared__ float tmp[4];
    float re = blockSum(val * cos2pi(x), tmp);
    float im = blockSum(val * sin2pi(x), tmp);
    if (m == 0) frq[b * 64 + k] = re * re + im * im;
}

// ======== reg: one block per (diagonal d, batch b) ========
__global__ __launch_bounds__(256) void regdiag_k(const unsigned short* __restrict__ ssm,
                                                 float* __restrict__ rg) {
    int d = blockIdx.x + 1, b = blockIdx.y, i = threadIdx.x;
    int col = i + d;
    bool ok = col < 256;
    float v = 0.f;
    if (ok) v = bf2f(ssm[(size_t)b * NT * NT + i * NT + col]);
    __shared__ float tmp[4];
    float s1 = blockSum(v, tmp);
    float s2 = blockSum(v * v, tmp);
    if (i == 0) {
        float outv = 0.f;
        if (d <= 254) {
            float mm = (float)(256 - d);
            float var = (s2 - s1 * s1 / mm) / (mm - 1.f);
            outv = sqrtf(fmaxf(var, 0.f)) * mm * 0.05f;
        }
        rg[b * 255 + (d - 1)] = outv;
    }
}

// ======== rppg DFT + fused temporal pearson (k==0 blocks) ========
__global__ __launch_bounds__(256) void rppgbin_k(const float* __restrict__ on,
                                                 const float* __restrict__ tg,
                                                 float* __restrict__ so,
                                                 float* __restrict__ st,
                                                 float* __restrict__ tq) {
    int k = blockIdx.x, b = blockIdx.y, t = threadIdx.x;
    const float* po = on + (size_t)b * NL;
    const float* pg = tg + (size_t)b * NL;
    float o1 = po[t], g1 = pg[t];
    float o2 = po[t + 256], g2 = pg[t + 256];
    bool h3 = t < 64;
    float o3 = h3 ? po[t + 512] : 0.f, g3 = h3 ? pg[t + 512] : 0.f;
    __shared__ float tmp[4];
    if (k == 0) {
        float S0 = blockSum(o1 + o2 + o3, tmp);
        float S1 = blockSum(g1 + g2 + g3, tmp);
        float S2 = blockSum(o1 * o1 + o2 * o2 + o3 * o3, tmp);
        float S3 = blockSum(g1 * g1 + g2 * g2 + g3 * g3, tmp);
        float S4 = blockSum(o1 * g1 + o2 * g2 + o3 * g3, tmp);
        if (t == 0) tq[3 * b + 0] = pearson1m(S0, S1, S2, S3, S4, 576.f);
        __syncthreads();
    }
    float reo, imo, reg_, img;
    {
        float x1 = (float)((t * k) % NL) * (1.f / 576.f);
        float c1 = cos2pi(x1), s1 = sin2pi(x1);
        float x2 = (float)(((t + 256) * k) % NL) * (1.f / 576.f);
        float c2 = cos2pi(x2), s2 = sin2pi(x2);
        reo = o1 * c1 + o2 * c2; imo = o1 * s1 + o2 * s2;
        reg_ = g1 * c1 + g2 * c2; img = g1 * s1 + g2 * s2;
        if (h3) {
            float x3 = (float)(((t + 512) * k) % NL) * (1.f / 576.f);
            float c3 = cos2pi(x3), s3 = sin2pi(x3);
            reo = fmaf(o3, c3, reo); imo = fmaf(o3, s3, imo);
            reg_ = fmaf(g3, c3, reg_); img = fmaf(g3, s3, img);
        }
    }
    float RO = blockSum(reo, tmp);
    float IO = blockSum(imo, tmp);
    float RG = blockSum(reg_, tmp);
    float IG = blockSum(img, tmp);
    if (t == 0) {
        so[b * 288 + k] = RO * RO + IO * IO;
        st[b * 288 + k] = RG * RG + IG * IG;
    }
}

// ======== rppg finalize: psd pearson + partition ========
__global__ __launch_bounds__(256) void rppgfin_k(const float* __restrict__ so,
                                                 const float* __restrict__ st,
                                                 float* __restrict__ tq) {
    int b = blockIdx.x, t = threadIdx.x;
    const float* SO = so + (size_t)b * 288;
    const float* ST = st + (size_t)b * 288;
    float a0 = SO[t], b0 = ST[t];
    bool h2 = t < 32;
    float a1 = h2 ? SO[t + 256] : 0.f, b1 = h2 ? ST[t + 256] : 0.f;
    __shared__ float tmp[4];
    float Mo = blockMax(fmaxf(a0, a1), tmp);
    float Mg = blockMax(fmaxf(b0, b1), tmp);
    if (Mo <= 0.f) Mo = 1.f;
    if (Mg <= 0.f) Mg = 1.f;
    float n0 = a0 / Mo, m0 = b0 / Mg;
    float n1 = a1 / Mo, m1 = b1 / Mg;
    float S0 = blockSum(n0 + n1, tmp);
    float S1 = blockSum(m0 + m1, tmp);
    float S2 = blockSum(n0 * n0 + n1 * n1, tmp);
    float S3 = blockSum(m0 * m0 + m1 * m1, tmp);
    float S4 = blockSum(n0 * m0 + n1 * m1, tmp);
    float bt0 = (t >= 9 && t < 57) ? a0 : 0.f;
    float TT = blockSum(a0 + a1, tmp);
    float TB = blockSum(bt0, tmp);
    if (t == 0) {
        tq[3 * b + 1] = pearson1m(S0, S1, S2, S3, S4, 288.f);
        tq[3 * b + 2] = (TB > 0.f) ? (TT / TB - 1.f) : 0.f;
    }
}

// ======== final combine (absorbs freq finalize) — FLOAT32 outputs ========
__global__ __launch_bounds__(256) void final_k(const float* __restrict__ ws,
                                               float* __restrict__ out) {
    __shared__ float tmp[4];
    int tid = threadIdx.x;
    const float* p1 = ws + OFF_P1;
    float a = 0.f, bsum = 0.f;
    for (int i = tid; i < 32768; i += 256) { a += p1[2 * i]; bsum += p1[2 * i + 1]; }
    float S0 = blockSum(a, tmp);
    float S1 = blockSum(bsum, tmp);
    const float* pw = ws + OFF_PW;
    float c0 = 0.f, c1 = 0.f;
    for (int i = tid; i < 128; i += 256) { c0 += pw[2 * i]; c1 += pw[2 * i + 1]; }
    float W0 = blockSum(c0, tmp);
    float W1 = blockSum(c1, tmp);
    const float* frq = ws + OFF_FRQ;
    float fqv = 0.f;
    if (tid < 128) {
        float Ft = 0.f, Fb = 0.f;
        for (int k = 0; k < 64; k++) {
            float v = frq[tid * 64 + k];
            Ft += v;
            if (k >= 2 && k < 12) Fb += v;
        }
        if (Fb > 0.f) fqv = Ft / Fb - 1.f;
    }
    float Fq = blockSum(fqv, tmp);
    const float* rg = ws + OFF_RG;
    float e = 0.f;
    for (int i = tid; i < 32640; i += 256) e += rg[i];
    float Rg = blockSum(e, tmp);
    const float* tq = ws + OFF_RPG;
    float g0 = 0.f, g1 = 0.f, g2 = 0.f;
    for (int i = tid; i < 128; i += 256) {
        g0 += tq[3 * i]; g1 += tq[3 * i + 1]; g2 += tq[3 * i + 2];
    }
    float R0 = blockSum(g0, tmp);
    float R1 = blockSum(g1, tmp);
    float R2 = blockSum(g2, tmp);
    if (tid == 0) {
        float loss_pyr  = 0.5f * (S1 / 8388608.f + W1 / 32768.f + S0 / 32768.f + W0 / 128.f);
        float loss_r    = 0.5f * Rg / (128.f * 254.f);
        float loss_f    = 0.2f * Fq / 128.f;
        float loss_rppg = 0.5f * (R0 + R1 + R2) / 128.f;
        float total = loss_rppg + loss_pyr + loss_r + loss_f;
        out[0] = total;
        out[1] = loss_pyr;
        out[2] = loss_rppg;
        out[3] = loss_r;
        out[4] = loss_f;
    }
}

extern "C" void kernel_launch(void* const* d_in, const int* in_sizes, int n_in,
                              void* d_out, int out_size, void* d_ws, size_t ws_size,
                              hipStream_t stream) {
    const float* pyr_on  = (const float*)d_in[0];
    const float* pyr_tg  = (const float*)d_in[1];
    const float* rppg_on = (const float*)d_in[2];
    const float* rppg_tg = (const float*)d_in[3];
    float* ws = (float*)d_ws;
    unsigned short* ssm_on = (unsigned short*)((char*)d_ws + OFF_SSM_ON_B);
    unsigned short* ssm_tg = (unsigned short*)((char*)d_ws + OFF_SSM_TG_B);
    float* out = (float*)d_out;

    gram9_k<<<4096, 256, 0, stream>>>(pyr_on, pyr_tg, ssm_on, ssm_tg);
    pearson256w_k<<<32768, 256, 0, stream>>>(ssm_on, ssm_tg, ws + OFF_P1,
                                             ws + OFF_WON, ws + OFF_WTG);
    pearsonW_k<<<NB, 256, 0, stream>>>(ws + OFF_WON, ws + OFF_WTG, ws + OFF_PW);
    freqbin_k<<<dim3(64, NB), 256, 0, stream>>>(ws + OFF_WON, ws + OFF_FRQ);
    regdiag_k<<<dim3(255, NB), 256, 0, stream>>>(ssm_on, ws + OFF_RG);
    rppgbin_k<<<dim3(288, NB), 256, 0, stream>>>(rppg_on, rppg_tg,
                                                 ws + OFF_SO, ws + OFF_ST, ws + OFF_RPG);
    rppgfin_k<<<NB, 256, 0, stream>>>(ws + OFF_SO, ws + OFF_ST, ws + OFF_RPG);
    final_k<<<1, 256, 0, stream>>>(ws, out);
}

// Round 24
// 308.813 us; speedup vs baseline: 1.4667x; 1.0076x over previous
//
#include <hip/hip_runtime.h>
#include <hip/hip_bf16.h>

#define NB 128
#define NT 256
#define NC 768
#define NL 576

// ---- workspace layout (float offsets), all < 1.3 MB; ssms at 2 MiB+ ----
constexpr size_t OFF_P1    = 4096;     // 65536: per-ssm-row {1-corr, sqdiff}
constexpr size_t OFF_WON   = 135168;   // 32768: waves online
constexpr size_t OFF_WTG   = 167936;   // 32768: waves target
constexpr size_t OFF_PW    = 200704;   // 256:   per-batch wave {1-corr, sqdiff}
constexpr size_t OFF_FRQ   = 200960;   // 8192:  per (b,k) wave PSD bin
constexpr size_t OFF_RG    = 209280;   // 32640: per (b,diag) std*m/20
constexpr size_t OFF_RPG   = 241920;   // 384:   per-batch {temporal, psd-pearson, partition}
constexpr size_t OFF_SO    = 242304;   // 36864: rppg online PSD (b*288+k)
constexpr size_t OFF_ST    = 279168;   // 36864: rppg target PSD
constexpr size_t OFF_SSM_ON_B = (size_t)2 * 1024 * 1024;                 // bytes
constexpr size_t OFF_SSM_TG_B = OFF_SSM_ON_B + (size_t)NB * NT * NT * 2; // bytes

typedef __attribute__((ext_vector_type(8))) short short8v;   // 8 bf16 (4 VGPR)
typedef __attribute__((ext_vector_type(4))) float f32x4;     // MFMA acc

__device__ __forceinline__ unsigned short f2bf(float f) {
    __hip_bfloat16 h = __float2bfloat16(f);
    unsigned short u; __builtin_memcpy(&u, &h, 2); return u;
}
__device__ __forceinline__ float bf2f(unsigned short u) {
    __hip_bfloat16 h; __builtin_memcpy(&h, &u, 2); return __bfloat162float(h);
}

// libm-free sin/cos of 2*pi*x, |err| < 3e-5
__device__ __forceinline__ float sin2pi(float x) {
    x -= floorf(x + 0.5f);
    float x2 = x * x;
    float p = 3.8199526f;
    p = p * x2 - 15.094643f;
    p = p * x2 + 42.058693f;
    p = p * x2 - 76.705860f;
    p = p * x2 + 81.605249f;
    p = p * x2 - 41.341702f;
    p = p * x2 + 6.2831853f;
    return p * x;
}
__device__ __forceinline__ float cos2pi(float x) { return sin2pi(x + 0.25f); }

__device__ __forceinline__ float blockSum(float v, float* tmp) {
    int lane = threadIdx.x & 63, wid = threadIdx.x >> 6;
#pragma unroll
    for (int o = 32; o; o >>= 1) v += __shfl_down(v, o, 64);
    __syncthreads();
    if (lane == 0) tmp[wid] = v;
    __syncthreads();
    return tmp[0] + tmp[1] + tmp[2] + tmp[3];
}
__device__ __forceinline__ float blockMax(float v, float* tmp) {
    int lane = threadIdx.x & 63, wid = threadIdx.x >> 6;
#pragma unroll
    for (int o = 32; o; o >>= 1) v = fmaxf(v, __shfl_down(v, o, 64));
    __syncthreads();
    if (lane == 0) tmp[wid] = v;
    __syncthreads();
    return fmaxf(fmaxf(tmp[0], tmp[1]), fmaxf(tmp[2], tmp[3]));
}
__device__ __forceinline__ float pearson1m(float S0, float S1, float S2, float S3,
                                           float S4, float n) {
    float cov = (S4 - S0 * S1 / n) / (n - 1.f);
    float xs = sqrtf(fmaxf((S2 - S0 * S0 / n) / (n - 1.f), 0.f));
    float ys = sqrtf(fmaxf((S3 - S1 * S1 / n) / (n - 1.f), 0.f));
    float corr = fminf(1.f, fmaxf(-1.f, cov / (xs * ys + 1e-7f)));
    return 1.f - corr;
}

// ======== fused dispatch: gram (bid<4096) | rppg DFT + temporal pearson ========
// Gram path == r23 gram9 (byte-identical math): 64x64 tile, [128][32] chunk-XOR
// swizzled LDS (0 conflicts), fused norms in dead-LDS overlay.
// rppg path == r23 rppgbin (byte-identical): one block per (bin k, batch b).
// Independent work co-schedules on CUs: VALU-bound rppg fills gram latency bubbles.
#define LDS_HALF9 (128 * 32)
__global__ __launch_bounds__(256) void gramrppg_k(const float* __restrict__ on,
                                                  const float* __restrict__ tg,
                                                  const float* __restrict__ rppg_on,
                                                  const float* __restrict__ rppg_tg,
                                                  unsigned short* __restrict__ ssm_on,
                                                  unsigned short* __restrict__ ssm_tg,
                                                  float* __restrict__ ws) {
    __shared__ unsigned short lds[2 * LDS_HALF9];
    __shared__ float tmp[4];
    int bid = blockIdx.x;
    int t = threadIdx.x;

    if (bid >= 4096) {
        // ---------------- rppg path ----------------
        int q = bid - 4096;
        int k = q % 288, b = q / 288;
        const float* po = rppg_on + (size_t)b * NL;
        const float* pg = rppg_tg + (size_t)b * NL;
        float o1 = po[t], g1 = pg[t];
        float o2 = po[t + 256], g2 = pg[t + 256];
        bool h3 = t < 64;
        float o3 = h3 ? po[t + 512] : 0.f, g3 = h3 ? pg[t + 512] : 0.f;
        if (k == 0) {
            float S0 = blockSum(o1 + o2 + o3, tmp);
            float S1 = blockSum(g1 + g2 + g3, tmp);
            float S2 = blockSum(o1 * o1 + o2 * o2 + o3 * o3, tmp);
            float S3 = blockSum(g1 * g1 + g2 * g2 + g3 * g3, tmp);
            float S4 = blockSum(o1 * g1 + o2 * g2 + o3 * g3, tmp);
            if (t == 0) ws[OFF_RPG + 3 * b + 0] = pearson1m(S0, S1, S2, S3, S4, 576.f);
            __syncthreads();
        }
        float reo, imo, reg_, img;
        {
            float x1 = (float)((t * k) % NL) * (1.f / 576.f);
            float c1 = cos2pi(x1), s1 = sin2pi(x1);
            float x2 = (float)(((t + 256) * k) % NL) * (1.f / 576.f);
            float c2 = cos2pi(x2), s2 = sin2pi(x2);
            reo = o1 * c1 + o2 * c2; imo = o1 * s1 + o2 * s2;
            reg_ = g1 * c1 + g2 * c2; img = g1 * s1 + g2 * s2;
            if (h3) {
                float x3 = (float)(((t + 512) * k) % NL) * (1.f / 576.f);
                float c3 = cos2pi(x3), s3 = sin2pi(x3);
                reo = fmaf(o3, c3, reo); imo = fmaf(o3, s3, imo);
                reg_ = fmaf(g3, c3, reg_); img = fmaf(g3, s3, img);
            }
        }
        float RO = blockSum(reo, tmp);
        float IO = blockSum(imo, tmp);
        float RG = blockSum(reg_, tmp);
        float IG = blockSum(img, tmp);
        if (t == 0) {
            ws[OFF_SO + b * 288 + k] = RO * RO + IO * IO;
            ws[OFF_ST + b * 288 + k] = RG * RG + IG * IG;
        }
        return;
    }

    // ---------------- gram path ----------------
    int lin = bid;
    int xcd = lin & 7, m = lin >> 3;
    int pair = (m >> 4) * 8 + xcd;
    int tile = m & 15;
    int rt = tile >> 2, ct = tile & 3;
    int b = pair >> 1, tau = pair & 1;
    const float* X = tau ? tg : on;
    unsigned short* S = (tau ? ssm_tg : ssm_on) + (size_t)b * NT * NT;

    int wave = t >> 6, lane = t & 63;
    int fr = lane & 15, fq = lane >> 4;
    int wr = (wave >> 1) * 32, wc = (wave & 1) * 32;

    int rl = t >> 1, h = t & 1;
    int grow = (rl < 64) ? (rt * 64 + rl) : (ct * 64 + (rl - 64));
    const float* src = X + ((size_t)b * NT + grow) * NC + h * 16;
    int swl = (rl >> 1) & 3;
    int stoff0 = rl * 32 + 8 * ((2 * h) ^ swl);
    int stoff1 = rl * 32 + 8 * ((2 * h + 1) ^ swl);
    float sq = 0.f;

    int fsw = (fr >> 1) & 3;
    int offA0 = (wr + fr) * 32 + 8 * (fq ^ fsw);
    int offA1 = (wr + 16 + fr) * 32 + 8 * (fq ^ fsw);
    int offB0 = (64 + wc + fr) * 32 + 8 * (fq ^ fsw);
    int offB1 = (64 + wc + 16 + fr) * 32 + 8 * (fq ^ fsw);

    f32x4 acc[2][2] = {};

    {
        float4 a = *reinterpret_cast<const float4*>(src);
        float4 bb = *reinterpret_cast<const float4*>(src + 4);
        float4 cc = *reinterpret_cast<const float4*>(src + 8);
        float4 d = *reinterpret_cast<const float4*>(src + 12);
        sq += a.x * a.x + a.y * a.y + a.z * a.z + a.w * a.w;
        sq += bb.x * bb.x + bb.y * bb.y + bb.z * bb.z + bb.w * bb.w;
        sq += cc.x * cc.x + cc.y * cc.y + cc.z * cc.z + cc.w * cc.w;
        sq += d.x * d.x + d.y * d.y + d.z * d.z + d.w * d.w;
        short8v v0, v1;
        v0[0] = (short)f2bf(a.x); v0[1] = (short)f2bf(a.y);
        v0[2] = (short)f2bf(a.z); v0[3] = (short)f2bf(a.w);
        v0[4] = (short)f2bf(bb.x); v0[5] = (short)f2bf(bb.y);
        v0[6] = (short)f2bf(bb.z); v0[7] = (short)f2bf(bb.w);
        v1[0] = (short)f2bf(cc.x); v1[1] = (short)f2bf(cc.y);
        v1[2] = (short)f2bf(cc.z); v1[3] = (short)f2bf(cc.w);
        v1[4] = (short)f2bf(d.x); v1[5] = (short)f2bf(d.y);
        v1[6] = (short)f2bf(d.z); v1[7] = (short)f2bf(d.w);
        *reinterpret_cast<short8v*>(&lds[stoff0]) = v0;
        *reinterpret_cast<short8v*>(&lds[stoff1]) = v1;
    }
    __syncthreads();

    int cur = 0;
#pragma unroll 1
    for (int s = 0; s < 24; s++) {
        unsigned short* rb = &lds[cur * LDS_HALF9];
        short8v A0 = *reinterpret_cast<short8v*>(rb + offA0);
        short8v A1 = *reinterpret_cast<short8v*>(rb + offA1);
        short8v B0 = *reinterpret_cast<short8v*>(rb + offB0);
        short8v B1 = *reinterpret_cast<short8v*>(rb + offB1);
        float4 a, bb, cc, d;
        if (s < 23) {
            const float* p = src + 32 * (s + 1);
            a = *reinterpret_cast<const float4*>(p);
            bb = *reinterpret_cast<const float4*>(p + 4);
            cc = *reinterpret_cast<const float4*>(p + 8);
            d = *reinterpret_cast<const float4*>(p + 12);
        }
        acc[0][0] = __builtin_amdgcn_mfma_f32_16x16x32_bf16(A0, B0, acc[0][0], 0, 0, 0);
        acc[0][1] = __builtin_amdgcn_mfma_f32_16x16x32_bf16(A0, B1, acc[0][1], 0, 0, 0);
        acc[1][0] = __builtin_amdgcn_mfma_f32_16x16x32_bf16(A1, B0, acc[1][0], 0, 0, 0);
        acc[1][1] = __builtin_amdgcn_mfma_f32_16x16x32_bf16(A1, B1, acc[1][1], 0, 0, 0);
        if (s < 23) {
            unsigned short* wbuf = &lds[(cur ^ 1) * LDS_HALF9];
            sq += a.x * a.x + a.y * a.y + a.z * a.z + a.w * a.w;
            sq += bb.x * bb.x + bb.y * bb.y + bb.z * bb.z + bb.w * bb.w;
            sq += cc.x * cc.x + cc.y * cc.y + cc.z * cc.z + cc.w * cc.w;
            sq += d.x * d.x + d.y * d.y + d.z * d.z + d.w * d.w;
            short8v v0, v1;
            v0[0] = (short)f2bf(a.x); v0[1] = (short)f2bf(a.y);
            v0[2] = (short)f2bf(a.z); v0[3] = (short)f2bf(a.w);
            v0[4] = (short)f2bf(bb.x); v0[5] = (short)f2bf(bb.y);
            v0[6] = (short)f2bf(bb.z); v0[7] = (short)f2bf(bb.w);
            v1[0] = (short)f2bf(cc.x); v1[1] = (short)f2bf(cc.y);
            v1[2] = (short)f2bf(cc.z); v1[3] = (short)f2bf(cc.w);
            v1[4] = (short)f2bf(d.x); v1[5] = (short)f2bf(d.y);
            v1[6] = (short)f2bf(d.z); v1[7] = (short)f2bf(d.w);
            *reinterpret_cast<short8v*>(wbuf + stoff0) = v0;
            *reinterpret_cast<short8v*>(wbuf + stoff1) = v1;
        }
        __syncthreads();
        cur ^= 1;
    }
    float* invp = reinterpret_cast<float*>(lds);
    {
        float v = sq + __shfl_xor(sq, 1, 64);
        if (h == 0) invp[rl] = 1.f / sqrtf(v);
    }
    __syncthreads();
#pragma unroll
    for (int f = 0; f < 2; f++) {
        int rowl = wr + 16 * f + 4 * fq;
#pragma unroll
        for (int g = 0; g < 2; g++) {
            int coll = wc + 16 * g + fr;
            float ic = invp[64 + coll];
            int gcol = ct * 64 + coll;
#pragma unroll
            for (int r = 0; r < 4; r++)
                S[(size_t)(rt * 64 + rowl + r) * NT + gcol] =
                    f2bf(acc[f][g][r] * invp[rowl + r] * ic);
        }
    }
}

// ======== per-ssm-row pearson + sqdiff + wave emit; single-barrier reduce ========
__global__ __launch_bounds__(256) void pearson256w_k(const unsigned short* __restrict__ A,
                                                     const unsigned short* __restrict__ Bv,
                                                     float* __restrict__ part,
                                                     float* __restrict__ won,
                                                     float* __restrict__ wtg) {
    size_t base = (size_t)blockIdx.x * NT;
    int tid = threadIdx.x;
    int lane = tid & 63, wid = tid >> 6;
    float o = bf2f(A[base + tid]), g = bf2f(Bv[base + tid]);
    float v6[6] = {o, g, o * o, g * g, o * g, (o - g) * (o - g)};
    __shared__ float tmp[4][6];
#pragma unroll
    for (int j = 0; j < 6; j++) {
        float x = v6[j];
#pragma unroll
        for (int off = 32; off; off >>= 1) x += __shfl_down(x, off, 64);
        v6[j] = x;
    }
    if (lane == 0) {
#pragma unroll
        for (int j = 0; j < 6; j++) tmp[wid][j] = v6[j];
    }
    __syncthreads();
    if (tid == 0) {
        float S[6];
#pragma unroll
        for (int j = 0; j < 6; j++)
            S[j] = tmp[0][j] + tmp[1][j] + tmp[2][j] + tmp[3][j];
        part[2 * blockIdx.x + 0] = pearson1m(S[0], S[1], S[2], S[3], S[4], 256.f);
        part[2 * blockIdx.x + 1] = S[5];
        won[blockIdx.x] = S[0] * (1.f / NT);
        wtg[blockIdx.x] = S[1] * (1.f / NT);
    }
}

// ======== wave pearson + sqdiff (f32) ========
__global__ __launch_bounds__(256) void pearsonW_k(const float* __restrict__ A,
                                                  const float* __restrict__ Bv,
                                                  float* __restrict__ part) {
    size_t base = (size_t)blockIdx.x * NT;
    int tid = threadIdx.x;
    float o = A[base + tid], g = Bv[base + tid];
    __shared__ float tmp[4];
    float S0 = blockSum(o, tmp);
    float S1 = blockSum(g, tmp);
    float S2 = blockSum(o * o, tmp);
    float S3 = blockSum(g * g, tmp);
    float S4 = blockSum(o * g, tmp);
    float S5 = blockSum((o - g) * (o - g), tmp);
    if (tid == 0) {
        part[2 * blockIdx.x + 0] = pearson1m(S0, S1, S2, S3, S4, 256.f);
        part[2 * blockIdx.x + 1] = S5;
    }
}

// ======== freq: one block per (bin k, batch b) ========
__global__ __launch_bounds__(256) void freqbin_k(const float* __restrict__ w,
                                                 float* __restrict__ frq) {
    int k = blockIdx.x, b = blockIdx.y, m = threadIdx.x;
    float val = w[b * NT + m];
    float x = (float)((m * k) & 255) * (1.f / 256.f);
    __shared__ float tmp[4];
    float re = blockSum(val * cos2pi(x), tmp);
    float im = blockSum(val * sin2pi(x), tmp);
    if (m == 0) frq[b * 64 + k] = re * re + im * im;
}

// ======== reg: one block per (diagonal d, batch b) ========
__global__ __launch_bounds__(256) void regdiag_k(const unsigned short* __restrict__ ssm,
                                                 float* __restrict__ rg) {
    int d = blockIdx.x + 1, b = blockIdx.y, i = threadIdx.x;
    int col = i + d;
    bool ok = col < 256;
    float v = 0.f;
    if (ok) v = bf2f(ssm[(size_t)b * NT * NT + i * NT + col]);
    __shared__ float tmp[4];
    float s1 = blockSum(v, tmp);
    float s2 = blockSum(v * v, tmp);
    if (i == 0) {
        float outv = 0.f;
        if (d <= 254) {
            float mm = (float)(256 - d);
            float var = (s2 - s1 * s1 / mm) / (mm - 1.f);
            outv = sqrtf(fmaxf(var, 0.f)) * mm * 0.05f;
        }
        rg[b * 255 + (d - 1)] = outv;
    }
}

// ======== rppg finalize: psd pearson + partition ========
__global__ __launch_bounds__(256) void rppgfin_k(const float* __restrict__ so,
                                                 const float* __restrict__ st,
                                                 float* __restrict__ tq) {
    int b = blockIdx.x, t = threadIdx.x;
    const float* SO = so + (size_t)b * 288;
    const float* ST = st + (size_t)b * 288;
    float a0 = SO[t], b0 = ST[t];
    bool h2 = t < 32;
    float a1 = h2 ? SO[t + 256] : 0.f, b1 = h2 ? ST[t + 256] : 0.f;
    __shared__ float tmp[4];
    float Mo = blockMax(fmaxf(a0, a1), tmp);
    float Mg = blockMax(fmaxf(b0, b1), tmp);
    if (Mo <= 0.f) Mo = 1.f;
    if (Mg <= 0.f) Mg = 1.f;
    float n0 = a0 / Mo, m0 = b0 / Mg;
    float n1 = a1 / Mo, m1 = b1 / Mg;
    float S0 = blockSum(n0 + n1, tmp);
    float S1 = blockSum(m0 + m1, tmp);
    float S2 = blockSum(n0 * n0 + n1 * n1, tmp);
    float S3 = blockSum(m0 * m0 + m1 * m1, tmp);
    float S4 = blockSum(n0 * m0 + n1 * m1, tmp);
    float bt0 = (t >= 9 && t < 57) ? a0 : 0.f;
    float TT = blockSum(a0 + a1, tmp);
    float TB = blockSum(bt0, tmp);
    if (t == 0) {
        tq[3 * b + 1] = pearson1m(S0, S1, S2, S3, S4, 288.f);
        tq[3 * b + 2] = (TB > 0.f) ? (TT / TB - 1.f) : 0.f;
    }
}

// ======== final combine (absorbs freq finalize) — FLOAT32 outputs ========
__global__ __launch_bounds__(256) void final_k(const float* __restrict__ ws,
                                               float* __restrict__ out) {
    __shared__ float tmp[4];
    int tid = threadIdx.x;
    const float* p1 = ws + OFF_P1;
    float a = 0.f, bsum = 0.f;
    for (int i = tid; i < 32768; i += 256) { a += p1[2 * i]; bsum += p1[2 * i + 1]; }
    float S0 = blockSum(a, tmp);
    float S1 = blockSum(bsum, tmp);
    const float* pw = ws + OFF_PW;
    float c0 = 0.f, c1 = 0.f;
    for (int i = tid; i < 128; i += 256) { c0 += pw[2 * i]; c1 += pw[2 * i + 1]; }
    float W0 = blockSum(c0, tmp);
    float W1 = blockSum(c1, tmp);
    const float* frq = ws + OFF_FRQ;
    float fqv = 0.f;
    if (tid < 128) {
        float Ft = 0.f, Fb = 0.f;
        for (int k = 0; k < 64; k++) {
            float v = frq[tid * 64 + k];
            Ft += v;
            if (k >= 2 && k < 12) Fb += v;
        }
        if (Fb > 0.f) fqv = Ft / Fb - 1.f;
    }
    float Fq = blockSum(fqv, tmp);
    const float* rg = ws + OFF_RG;
    float e = 0.f;
    for (int i = tid; i < 32640; i += 256) e += rg[i];
    float Rg = blockSum(e, tmp);
    const float* tq = ws + OFF_RPG;
    float g0 = 0.f, g1 = 0.f, g2 = 0.f;
    for (int i = tid; i < 128; i += 256) {
        g0 += tq[3 * i]; g1 += tq[3 * i + 1]; g2 += tq[3 * i + 2];
    }
    float R0 = blockSum(g0, tmp);
    float R1 = blockSum(g1, tmp);
    float R2 = blockSum(g2, tmp);
    if (tid == 0) {
        float loss_pyr  = 0.5f * (S1 / 8388608.f + W1 / 32768.f + S0 / 32768.f + W0 / 128.f);
        float loss_r    = 0.5f * Rg / (128.f * 254.f);
        float loss_f    = 0.2f * Fq / 128.f;
        float loss_rppg = 0.5f * (R0 + R1 + R2) / 128.f;
        float total = loss_rppg + loss_pyr + loss_r + loss_f;
        out[0] = total;
        out[1] = loss_pyr;
        out[2] = loss_rppg;
        out[3] = loss_r;
        out[4] = loss_f;
    }
}

extern "C" void kernel_launch(void* const* d_in, const int* in_sizes, int n_in,
                              void* d_out, int out_size, void* d_ws, size_t ws_size,
                              hipStream_t stream) {
    const float* pyr_on  = (const float*)d_in[0];
    const float* pyr_tg  = (const float*)d_in[1];
    const float* rppg_on = (const float*)d_in[2];
    const float* rppg_tg = (const float*)d_in[3];
    float* ws = (float*)d_ws;
    unsigned short* ssm_on = (unsigned short*)((char*)d_ws + OFF_SSM_ON_B);
    unsigned short* ssm_tg = (unsigned short*)((char*)d_ws + OFF_SSM_TG_B);
    float* out = (float*)d_out;

    gramrppg_k<<<4096 + 36864, 256, 0, stream>>>(pyr_on, pyr_tg, rppg_on, rppg_tg,
                                                 ssm_on, ssm_tg, ws);
    pearson256w_k<<<32768, 256, 0, stream>>>(ssm_on, ssm_tg, ws + OFF_P1,
                                             ws + OFF_WON, ws + OFF_WTG);
    pearsonW_k<<<NB, 256, 0, stream>>>(ws + OFF_WON, ws + OFF_WTG, ws + OFF_PW);
    freqbin_k<<<dim3(64, NB), 256, 0, stream>>>(ws + OFF_WON, ws + OFF_FRQ);
    regdiag_k<<<dim3(255, NB), 256, 0, stream>>>(ssm_on, ws + OFF_RG);
    rppgfin_k<<<NB, 256, 0, stream>>>(ws + OFF_SO, ws + OFF_ST, ws + OFF_RPG);
    final_k<<<1, 256, 0, stream>>>(ws, out);
}

// Round 25
// 257.216 us; speedup vs baseline: 1.7609x; 1.2006x over previous
//
#include <hip/hip_runtime.h>
#include <hip/hip_bf16.h>

#define NB 128
#define NT 256
#define NC 768
#define NL 576

// ---- workspace layout (float offsets), all < 1.3 MB; ssms at 2 MiB+ ----
constexpr size_t OFF_P1    = 4096;     // 65536: per-ssm-row {1-corr, sqdiff}
constexpr size_t OFF_WON   = 135168;   // 32768: waves online
constexpr size_t OFF_WTG   = 167936;   // 32768: waves target
constexpr size_t OFF_PW    = 200704;   // 256:   per-batch wave {1-corr, sqdiff}
constexpr size_t OFF_FRQ   = 200960;   // 8192:  per (b,k) wave PSD bin
constexpr size_t OFF_RG    = 209280;   // 32640: per (b,diag) std*m/20
constexpr size_t OFF_RPG   = 241920;   // 384:   per-batch {temporal, psd-pearson, partition}
constexpr size_t OFF_SO    = 242304;   // 36864: rppg online PSD (b*288+k)
constexpr size_t OFF_ST    = 279168;   // 36864: rppg target PSD
constexpr size_t OFF_SSM_ON_B = (size_t)2 * 1024 * 1024;                 // bytes
constexpr size_t OFF_SSM_TG_B = OFF_SSM_ON_B + (size_t)NB * NT * NT * 2; // bytes

typedef __attribute__((ext_vector_type(8))) short short8v;   // 8 bf16 (4 VGPR)
typedef __attribute__((ext_vector_type(4))) short short4v;   // 4 bf16 (2 VGPR)
typedef __attribute__((ext_vector_type(4))) float f32x4;     // MFMA acc

__device__ __forceinline__ unsigned short f2bf(float f) {
    __hip_bfloat16 h = __float2bfloat16(f);
    unsigned short u; __builtin_memcpy(&u, &h, 2); return u;
}
__device__ __forceinline__ float bf2f(unsigned short u) {
    __hip_bfloat16 h; __builtin_memcpy(&h, &u, 2); return __bfloat162float(h);
}

// libm-free sin/cos of 2*pi*x, |err| < 3e-5
__device__ __forceinline__ float sin2pi(float x) {
    x -= floorf(x + 0.5f);
    float x2 = x * x;
    float p = 3.8199526f;
    p = p * x2 - 15.094643f;
    p = p * x2 + 42.058693f;
    p = p * x2 - 76.705860f;
    p = p * x2 + 81.605249f;
    p = p * x2 - 41.341702f;
    p = p * x2 + 6.2831853f;
    return p * x;
}
__device__ __forceinline__ float cos2pi(float x) { return sin2pi(x + 0.25f); }

__device__ __forceinline__ float blockSum(float v, float* tmp) {
    int lane = threadIdx.x & 63, wid = threadIdx.x >> 6;
#pragma unroll
    for (int o = 32; o; o >>= 1) v += __shfl_down(v, o, 64);
    __syncthreads();
    if (lane == 0) tmp[wid] = v;
    __syncthreads();
    return tmp[0] + tmp[1] + tmp[2] + tmp[3];
}
__device__ __forceinline__ float blockMax(float v, float* tmp) {
    int lane = threadIdx.x & 63, wid = threadIdx.x >> 6;
#pragma unroll
    for (int o = 32; o; o >>= 1) v = fmaxf(v, __shfl_down(v, o, 64));
    __syncthreads();
    if (lane == 0) tmp[wid] = v;
    __syncthreads();
    return fmaxf(fmaxf(tmp[0], tmp[1]), fmaxf(tmp[2], tmp[3]));
}
__device__ __forceinline__ float pearson1m(float S0, float S1, float S2, float S3,
                                           float S4, float n) {
    float cov = (S4 - S0 * S1 / n) / (n - 1.f);
    float xs = sqrtf(fmaxf((S2 - S0 * S0 / n) / (n - 1.f), 0.f));
    float ys = sqrtf(fmaxf((S3 - S1 * S1 / n) / (n - 1.f), 0.f));
    float corr = fminf(1.f, fmaxf(-1.f, cov / (xs * ys + 1e-7f)));
    return 1.f - corr;
}

// ======== fused dispatch: gram (bid<4096) | rppg DFT + temporal pearson ========
#define LDS_HALF9 (128 * 32)
__global__ __launch_bounds__(256) void gramrppg_k(const float* __restrict__ on,
                                                  const float* __restrict__ tg,
                                                  const float* __restrict__ rppg_on,
                                                  const float* __restrict__ rppg_tg,
                                                  unsigned short* __restrict__ ssm_on,
                                                  unsigned short* __restrict__ ssm_tg,
                                                  float* __restrict__ ws) {
    __shared__ unsigned short lds[2 * LDS_HALF9];
    __shared__ float tmp[4];
    int bid = blockIdx.x;
    int t = threadIdx.x;

    if (bid >= 4096) {
        // ---------------- rppg path ----------------
        int q = bid - 4096;
        int k = q % 288, b = q / 288;
        const float* po = rppg_on + (size_t)b * NL;
        const float* pg = rppg_tg + (size_t)b * NL;
        float o1 = po[t], g1 = pg[t];
        float o2 = po[t + 256], g2 = pg[t + 256];
        bool h3 = t < 64;
        float o3 = h3 ? po[t + 512] : 0.f, g3 = h3 ? pg[t + 512] : 0.f;
        if (k == 0) {
            float S0 = blockSum(o1 + o2 + o3, tmp);
            float S1 = blockSum(g1 + g2 + g3, tmp);
            float S2 = blockSum(o1 * o1 + o2 * o2 + o3 * o3, tmp);
            float S3 = blockSum(g1 * g1 + g2 * g2 + g3 * g3, tmp);
            float S4 = blockSum(o1 * g1 + o2 * g2 + o3 * g3, tmp);
            if (t == 0) ws[OFF_RPG + 3 * b + 0] = pearson1m(S0, S1, S2, S3, S4, 576.f);
            __syncthreads();
        }
        float reo, imo, reg_, img;
        {
            float x1 = (float)((t * k) % NL) * (1.f / 576.f);
            float c1 = cos2pi(x1), s1 = sin2pi(x1);
            float x2 = (float)(((t + 256) * k) % NL) * (1.f / 576.f);
            float c2 = cos2pi(x2), s2 = sin2pi(x2);
            reo = o1 * c1 + o2 * c2; imo = o1 * s1 + o2 * s2;
            reg_ = g1 * c1 + g2 * c2; img = g1 * s1 + g2 * s2;
            if (h3) {
                float x3 = (float)(((t + 512) * k) % NL) * (1.f / 576.f);
                float c3 = cos2pi(x3), s3 = sin2pi(x3);
                reo = fmaf(o3, c3, reo); imo = fmaf(o3, s3, imo);
                reg_ = fmaf(g3, c3, reg_); img = fmaf(g3, s3, img);
            }
        }
        float RO = blockSum(reo, tmp);
        float IO = blockSum(imo, tmp);
        float RG = blockSum(reg_, tmp);
        float IG = blockSum(img, tmp);
        if (t == 0) {
            ws[OFF_SO + b * 288 + k] = RO * RO + IO * IO;
            ws[OFF_ST + b * 288 + k] = RG * RG + IG * IG;
        }
        return;
    }

    // ---------------- gram path (r23 gram9, byte-identical) ----------------
    int lin = bid;
    int xcd = lin & 7, m = lin >> 3;
    int pair = (m >> 4) * 8 + xcd;
    int tile = m & 15;
    int rt = tile >> 2, ct = tile & 3;
    int b = pair >> 1, tau = pair & 1;
    const float* X = tau ? tg : on;
    unsigned short* S = (tau ? ssm_tg : ssm_on) + (size_t)b * NT * NT;

    int wave = t >> 6, lane = t & 63;
    int fr = lane & 15, fq = lane >> 4;
    int wr = (wave >> 1) * 32, wc = (wave & 1) * 32;

    int rl = t >> 1, h = t & 1;
    int grow = (rl < 64) ? (rt * 64 + rl) : (ct * 64 + (rl - 64));
    const float* src = X + ((size_t)b * NT + grow) * NC + h * 16;
    int swl = (rl >> 1) & 3;
    int stoff0 = rl * 32 + 8 * ((2 * h) ^ swl);
    int stoff1 = rl * 32 + 8 * ((2 * h + 1) ^ swl);
    float sq = 0.f;

    int fsw = (fr >> 1) & 3;
    int offA0 = (wr + fr) * 32 + 8 * (fq ^ fsw);
    int offA1 = (wr + 16 + fr) * 32 + 8 * (fq ^ fsw);
    int offB0 = (64 + wc + fr) * 32 + 8 * (fq ^ fsw);
    int offB1 = (64 + wc + 16 + fr) * 32 + 8 * (fq ^ fsw);

    f32x4 acc[2][2] = {};

    {
        float4 a = *reinterpret_cast<const float4*>(src);
        float4 bb = *reinterpret_cast<const float4*>(src + 4);
        float4 cc = *reinterpret_cast<const float4*>(src + 8);
        float4 d = *reinterpret_cast<const float4*>(src + 12);
        sq += a.x * a.x + a.y * a.y + a.z * a.z + a.w * a.w;
        sq += bb.x * bb.x + bb.y * bb.y + bb.z * bb.z + bb.w * bb.w;
        sq += cc.x * cc.x + cc.y * cc.y + cc.z * cc.z + cc.w * cc.w;
        sq += d.x * d.x + d.y * d.y + d.z * d.z + d.w * d.w;
        short8v v0, v1;
        v0[0] = (short)f2bf(a.x); v0[1] = (short)f2bf(a.y);
        v0[2] = (short)f2bf(a.z); v0[3] = (short)f2bf(a.w);
        v0[4] = (short)f2bf(bb.x); v0[5] = (short)f2bf(bb.y);
        v0[6] = (short)f2bf(bb.z); v0[7] = (short)f2bf(bb.w);
        v1[0] = (short)f2bf(cc.x); v1[1] = (short)f2bf(cc.y);
        v1[2] = (short)f2bf(cc.z); v1[3] = (short)f2bf(cc.w);
        v1[4] = (short)f2bf(d.x); v1[5] = (short)f2bf(d.y);
        v1[6] = (short)f2bf(d.z); v1[7] = (short)f2bf(d.w);
        *reinterpret_cast<short8v*>(&lds[stoff0]) = v0;
        *reinterpret_cast<short8v*>(&lds[stoff1]) = v1;
    }
    __syncthreads();

    int cur = 0;
#pragma unroll 1
    for (int s = 0; s < 24; s++) {
        unsigned short* rb = &lds[cur * LDS_HALF9];
        short8v A0 = *reinterpret_cast<short8v*>(rb + offA0);
        short8v A1 = *reinterpret_cast<short8v*>(rb + offA1);
        short8v B0 = *reinterpret_cast<short8v*>(rb + offB0);
        short8v B1 = *reinterpret_cast<short8v*>(rb + offB1);
        float4 a, bb, cc, d;
        if (s < 23) {
            const float* p = src + 32 * (s + 1);
            a = *reinterpret_cast<const float4*>(p);
            bb = *reinterpret_cast<const float4*>(p + 4);
            cc = *reinterpret_cast<const float4*>(p + 8);
            d = *reinterpret_cast<const float4*>(p + 12);
        }
        acc[0][0] = __builtin_amdgcn_mfma_f32_16x16x32_bf16(A0, B0, acc[0][0], 0, 0, 0);
        acc[0][1] = __builtin_amdgcn_mfma_f32_16x16x32_bf16(A0, B1, acc[0][1], 0, 0, 0);
        acc[1][0] = __builtin_amdgcn_mfma_f32_16x16x32_bf16(A1, B0, acc[1][0], 0, 0, 0);
        acc[1][1] = __builtin_amdgcn_mfma_f32_16x16x32_bf16(A1, B1, acc[1][1], 0, 0, 0);
        if (s < 23) {
            unsigned short* wbuf = &lds[(cur ^ 1) * LDS_HALF9];
            sq += a.x * a.x + a.y * a.y + a.z * a.z + a.w * a.w;
            sq += bb.x * bb.x + bb.y * bb.y + bb.z * bb.z + bb.w * bb.w;
            sq += cc.x * cc.x + cc.y * cc.y + cc.z * cc.z + cc.w * cc.w;
            sq += d.x * d.x + d.y * d.y + d.z * d.z + d.w * d.w;
            short8v v0, v1;
            v0[0] = (short)f2bf(a.x); v0[1] = (short)f2bf(a.y);
            v0[2] = (short)f2bf(a.z); v0[3] = (short)f2bf(a.w);
            v0[4] = (short)f2bf(bb.x); v0[5] = (short)f2bf(bb.y);
            v0[6] = (short)f2bf(bb.z); v0[7] = (short)f2bf(bb.w);
            v1[0] = (short)f2bf(cc.x); v1[1] = (short)f2bf(cc.y);
            v1[2] = (short)f2bf(cc.z); v1[3] = (short)f2bf(cc.w);
            v1[4] = (short)f2bf(d.x); v1[5] = (short)f2bf(d.y);
            v1[6] = (short)f2bf(d.z); v1[7] = (short)f2bf(d.w);
            *reinterpret_cast<short8v*>(wbuf + stoff0) = v0;
            *reinterpret_cast<short8v*>(wbuf + stoff1) = v1;
        }
        __syncthreads();
        cur ^= 1;
    }
    float* invp = reinterpret_cast<float*>(lds);
    {
        float v = sq + __shfl_xor(sq, 1, 64);
        if (h == 0) invp[rl] = 1.f / sqrtf(v);
    }
    __syncthreads();
#pragma unroll
    for (int f = 0; f < 2; f++) {
        int rowl = wr + 16 * f + 4 * fq;
#pragma unroll
        for (int g = 0; g < 2; g++) {
            int coll = wc + 16 * g + fr;
            float ic = invp[64 + coll];
            int gcol = ct * 64 + coll;
#pragma unroll
            for (int r = 0; r < 4; r++)
                S[(size_t)(rt * 64 + rowl + r) * NT + gcol] =
                    f2bf(acc[f][g][r] * invp[rowl + r] * ic);
        }
    }
}

// ======== wave-per-row ssm pearson + sqdiff + wave emit (no barriers) ========
// Block = 4 waves = 4 rows; lane reads short4 (64 lanes x 8B = one 512B row).
__global__ __launch_bounds__(256) void pearsonrow_k(const unsigned short* __restrict__ A,
                                                    const unsigned short* __restrict__ Bv,
                                                    float* __restrict__ part,
                                                    float* __restrict__ won,
                                                    float* __restrict__ wtg) {
    int t = threadIdx.x;
    int lane = t & 63, wid = t >> 6;
    size_t row = (size_t)blockIdx.x * 4 + wid;
    size_t base = row * NT + lane * 4;
    short4v av = *reinterpret_cast<const short4v*>(&A[base]);
    short4v bv = *reinterpret_cast<const short4v*>(&Bv[base]);
    float s0 = 0.f, s1 = 0.f, s2 = 0.f, s3 = 0.f, s4 = 0.f, s5 = 0.f;
#pragma unroll
    for (int j = 0; j < 4; j++) {
        float o = bf2f((unsigned short)av[j]);
        float g = bf2f((unsigned short)bv[j]);
        s0 += o; s1 += g; s2 += o * o; s3 += g * g; s4 += o * g;
        s5 += (o - g) * (o - g);
    }
#pragma unroll
    for (int off = 32; off; off >>= 1) {
        s0 += __shfl_down(s0, off, 64);
        s1 += __shfl_down(s1, off, 64);
        s2 += __shfl_down(s2, off, 64);
        s3 += __shfl_down(s3, off, 64);
        s4 += __shfl_down(s4, off, 64);
        s5 += __shfl_down(s5, off, 64);
    }
    if (lane == 0) {
        part[2 * row + 0] = pearson1m(s0, s1, s2, s3, s4, 256.f);
        part[2 * row + 1] = s5;
        won[row] = s0 * (1.f / NT);
        wtg[row] = s1 * (1.f / NT);
    }
}

// ======== wave pearson + sqdiff (f32) ========
__global__ __launch_bounds__(256) void pearsonW_k(const float* __restrict__ A,
                                                  const float* __restrict__ Bv,
                                                  float* __restrict__ part) {
    size_t base = (size_t)blockIdx.x * NT;
    int tid = threadIdx.x;
    float o = A[base + tid], g = Bv[base + tid];
    __shared__ float tmp[4];
    float S0 = blockSum(o, tmp);
    float S1 = blockSum(g, tmp);
    float S2 = blockSum(o * o, tmp);
    float S3 = blockSum(g * g, tmp);
    float S4 = blockSum(o * g, tmp);
    float S5 = blockSum((o - g) * (o - g), tmp);
    if (tid == 0) {
        part[2 * blockIdx.x + 0] = pearson1m(S0, S1, S2, S3, S4, 256.f);
        part[2 * blockIdx.x + 1] = S5;
    }
}

// ======== wave-per-bin freq (4 bins/block, no barriers) ========
__global__ __launch_bounds__(256) void freqbin4_k(const float* __restrict__ w,
                                                  float* __restrict__ frq) {
    int t = threadIdx.x;
    int lane = t & 63, wid = t >> 6;
    int q = blockIdx.x * 4 + wid;            // 0..8191
    int k = q & 63, b = q >> 6;
    float re = 0.f, im = 0.f;
#pragma unroll
    for (int p = 0; p < 4; p++) {
        int mm = lane + 64 * p;
        float val = w[b * NT + mm];
        float x = (float)((mm * k) & 255) * (1.f / 256.f);
        re = fmaf(val, cos2pi(x), re);
        im = fmaf(val, sin2pi(x), im);
    }
#pragma unroll
    for (int off = 32; off; off >>= 1) {
        re += __shfl_down(re, off, 64);
        im += __shfl_down(im, off, 64);
    }
    if (lane == 0) frq[b * 64 + k] = re * re + im * im;
}

// ======== wave-per-diagonal reg (4 diags/block, no barriers) ========
__global__ __launch_bounds__(256) void regdiag4_k(const unsigned short* __restrict__ ssm,
                                                  float* __restrict__ rg) {
    int t = threadIdx.x;
    int lane = t & 63, wid = t >> 6;
    int b = blockIdx.x >> 6;
    int d = (blockIdx.x & 63) * 4 + wid + 1;      // 1..256
    if (d > 255) return;
    const unsigned short* S = ssm + (size_t)b * NT * NT;
    float s1 = 0.f, s2 = 0.f;
#pragma unroll
    for (int p = 0; p < 4; p++) {
        int i = lane + 64 * p;
        if (i + d < 256) {
            float v = bf2f(S[i * NT + i + d]);
            s1 += v; s2 += v * v;
        }
    }
#pragma unroll
    for (int off = 32; off; off >>= 1) {
        s1 += __shfl_down(s1, off, 64);
        s2 += __shfl_down(s2, off, 64);
    }
    if (lane == 0) {
        float outv = 0.f;
        if (d <= 254) {
            float mm = (float)(256 - d);
            float var = (s2 - s1 * s1 / mm) / (mm - 1.f);
            outv = sqrtf(fmaxf(var, 0.f)) * mm * 0.05f;
        }
        rg[b * 255 + (d - 1)] = outv;
    }
}

// ======== rppg finalize: psd pearson + partition ========
__global__ __launch_bounds__(256) void rppgfin_k(const float* __restrict__ so,
                                                 const float* __restrict__ st,
                                                 float* __restrict__ tq) {
    int b = blockIdx.x, t = threadIdx.x;
    const float* SO = so + (size_t)b * 288;
    const float* ST = st + (size_t)b * 288;
    float a0 = SO[t], b0 = ST[t];
    bool h2 = t < 32;
    float a1 = h2 ? SO[t + 256] : 0.f, b1 = h2 ? ST[t + 256] : 0.f;
    __shared__ float tmp[4];
    float Mo = blockMax(fmaxf(a0, a1), tmp);
    float Mg = blockMax(fmaxf(b0, b1), tmp);
    if (Mo <= 0.f) Mo = 1.f;
    if (Mg <= 0.f) Mg = 1.f;
    float n0 = a0 / Mo, m0 = b0 / Mg;
    float n1 = a1 / Mo, m1 = b1 / Mg;
    float S0 = blockSum(n0 + n1, tmp);
    float S1 = blockSum(m0 + m1, tmp);
    float S2 = blockSum(n0 * n0 + n1 * n1, tmp);
    float S3 = blockSum(m0 * m0 + m1 * m1, tmp);
    float S4 = blockSum(n0 * m0 + n1 * m1, tmp);
    float bt0 = (t >= 9 && t < 57) ? a0 : 0.f;
    float TT = blockSum(a0 + a1, tmp);
    float TB = blockSum(bt0, tmp);
    if (t == 0) {
        tq[3 * b + 1] = pearson1m(S0, S1, S2, S3, S4, 288.f);
        tq[3 * b + 2] = (TB > 0.f) ? (TT / TB - 1.f) : 0.f;
    }
}

// ======== final combine (absorbs freq finalize) — FLOAT32 outputs ========
__global__ __launch_bounds__(256) void final_k(const float* __restrict__ ws,
                                               float* __restrict__ out) {
    __shared__ float tmp[4];
    int tid = threadIdx.x;
    const float* p1 = ws + OFF_P1;
    float a = 0.f, bsum = 0.f;
    for (int i = tid; i < 32768; i += 256) { a += p1[2 * i]; bsum += p1[2 * i + 1]; }
    float S0 = blockSum(a, tmp);
    float S1 = blockSum(bsum, tmp);
    const float* pw = ws + OFF_PW;
    float c0 = 0.f, c1 = 0.f;
    for (int i = tid; i < 128; i += 256) { c0 += pw[2 * i]; c1 += pw[2 * i + 1]; }
    float W0 = blockSum(c0, tmp);
    float W1 = blockSum(c1, tmp);
    const float* frq = ws + OFF_FRQ;
    float fqv = 0.f;
    if (tid < 128) {
        float Ft = 0.f, Fb = 0.f;
        for (int k = 0; k < 64; k++) {
            float v = frq[tid * 64 + k];
            Ft += v;
            if (k >= 2 && k < 12) Fb += v;
        }
        if (Fb > 0.f) fqv = Ft / Fb - 1.f;
    }
    float Fq = blockSum(fqv, tmp);
    const float* rg = ws + OFF_RG;
    float e = 0.f;
    for (int i = tid; i < 32640; i += 256) e += rg[i];
    float Rg = blockSum(e, tmp);
    const float* tq = ws + OFF_RPG;
    float g0 = 0.f, g1 = 0.f, g2 = 0.f;
    for (int i = tid; i < 128; i += 256) {
        g0 += tq[3 * i]; g1 += tq[3 * i + 1]; g2 += tq[3 * i + 2];
    }
    float R0 = blockSum(g0, tmp);
    float R1 = blockSum(g1, tmp);
    float R2 = blockSum(g2, tmp);
    if (tid == 0) {
        float loss_pyr  = 0.5f * (S1 / 8388608.f + W1 / 32768.f + S0 / 32768.f + W0 / 128.f);
        float loss_r    = 0.5f * Rg / (128.f * 254.f);
        float loss_f    = 0.2f * Fq / 128.f;
        float loss_rppg = 0.5f * (R0 + R1 + R2) / 128.f;
        float total = loss_rppg + loss_pyr + loss_r + loss_f;
        out[0] = total;
        out[1] = loss_pyr;
        out[2] = loss_rppg;
        out[3] = loss_r;
        out[4] = loss_f;
    }
}

extern "C" void kernel_launch(void* const* d_in, const int* in_sizes, int n_in,
                              void* d_out, int out_size, void* d_ws, size_t ws_size,
                              hipStream_t stream) {
    const float* pyr_on  = (const float*)d_in[0];
    const float* pyr_tg  = (const float*)d_in[1];
    const float* rppg_on = (const float*)d_in[2];
    const float* rppg_tg = (const float*)d_in[3];
    float* ws = (float*)d_ws;
    unsigned short* ssm_on = (unsigned short*)((char*)d_ws + OFF_SSM_ON_B);
    unsigned short* ssm_tg = (unsigned short*)((char*)d_ws + OFF_SSM_TG_B);
    float* out = (float*)d_out;

    gramrppg_k<<<4096 + 36864, 256, 0, stream>>>(pyr_on, pyr_tg, rppg_on, rppg_tg,
                                                 ssm_on, ssm_tg, ws);
    pearsonrow_k<<<8192, 256, 0, stream>>>(ssm_on, ssm_tg, ws + OFF_P1,
                                           ws + OFF_WON, ws + OFF_WTG);
    regdiag4_k<<<8192, 256, 0, stream>>>(ssm_on, ws + OFF_RG);
    freqbin4_k<<<2048, 256, 0, stream>>>(ws + OFF_WON, ws + OFF_FRQ);
    pearsonW_k<<<NB, 256, 0, stream>>>(ws + OFF_WON, ws + OFF_WTG, ws + OFF_PW);
    rppgfin_k<<<NB, 256, 0, stream>>>(ws + OFF_SO, ws + OFF_ST, ws + OFF_RPG);
    final_k<<<1, 256, 0, stream>>>(ws, out);
}